// Round 8
// baseline (193.119 us; speedup 1.0000x reference)
//
#include <hip/hip_runtime.h>
#include <hip/hip_bf16.h>

// GAT layer: out = h = x @ W^T  (N=200000 x 128, fp32 in / fp32 out), then
// E=500 edges: out[dst] += 0.1 * leaky_relu(attn, 0.2) * h[src].
//
// K1 evidence trail:
//   R0/R2 scattered loads+stores:             154 MB @ 2.06 TB/s (75us)
//   R3/R4 scattered + 2-deep prefetch:        L2 poison (write amp 1.8-3.3x)
//   R5 contiguous loads, barrier convoy:      2.43 TB/s (64us)
//   R6 contiguous loads, barrier-free waves:  2.33 TB/s (66us)
//   R7 + coalesced stores (LDS transpose):    2.43 TB/s (64us); WRITE exactly
//      100 MB, FETCH 50.3 MB -> traffic is perfectly clean; BW still pinned.
//   harness fillBuffer: 6.4 TB/s same context -> machine can.
// Last untested cell of {contiguous?, deep?}: every clean config fully
// drains its single 8KB burst per iteration (pack consumes all loads) ->
// low outstanding-bytes duty cycle. R3/R4's poison came with SCATTERED
// footprints. R8 = R7 structure + 2-deep contiguous ping-pong prefetch
// (rawA/rawB statically named): >=8KB continuously in flight per wave.
// K2/K3 unchanged (race-free two-phase edge update).

typedef __attribute__((ext_vector_type(8))) short bf16x8;   // 8 bf16 = 4 VGPRs
typedef __attribute__((ext_vector_type(4))) float f32x4;

#define W_PAD 136   // 128 + 8 bf16; 272 B row stride (16B-aligned)
#define S_PAD 132   // f32 scratch row stride (528 B): 4-bank shift per row

__device__ __forceinline__ void load_tile(const float* __restrict__ x,
                                          int t, int lane, float4 (&raw)[8]) {
  const float* xt = x + (long)t * 2048;   // 16*128 floats = 8 KB tile
  #pragma unroll
  for (int i = 0; i < 8; ++i)             // 1 KB contiguous per instruction
    raw[i] = *reinterpret_cast<const float4*>(xt + (i * 64 + lane) * 4);
}

__global__ __launch_bounds__(256, 3) void gat_gemm_kernel(
    const float* __restrict__ x,
    const float* __restrict__ W,
    float* __restrict__ out,
    int N) {
  __shared__ __hip_bfloat16 Ws[128 * W_PAD];      // 34816 B
  __shared__ __hip_bfloat16 Xs[4][16 * W_PAD];    // 4 x 4352 B per-wave slices
  // total 52224 B -> 3 blocks/CU; slice doubles as 8x132-f32 store scratch.

  const int tid = threadIdx.x;

  // Stage W (128x128 fp32 = 64 KB) into LDS as bf16. One-time per block.
  #pragma unroll
  for (int it = 0; it < 16; ++it) {
    int seg = tid + it * 256;          // 0..4095 float4 segments
    int row = seg >> 5;                // 32 segments per 128-col row
    int off = (seg & 31) * 4;
    float4 v = *reinterpret_cast<const float4*>(&W[row * 128 + off]);
    union { ushort4 u4; __hip_bfloat16 h[4]; } wpk;
    wpk.h[0] = __float2bfloat16(v.x);
    wpk.h[1] = __float2bfloat16(v.y);
    wpk.h[2] = __float2bfloat16(v.z);
    wpk.h[3] = __float2bfloat16(v.w);
    *reinterpret_cast<ushort4*>(&Ws[row * W_PAD + off]) = wpk.u4;
  }
  __syncthreads();   // one-time; no barriers after this point

  const int wave = tid >> 6;
  const int lane = tid & 63;
  const int m = lane & 15;     // W row (= out col) in A-frag / x row in B-frag
  const int q = lane >> 4;     // quad: k-subchunk q*8, D reg row q*4+j

  __hip_bfloat16* xs = &Xs[wave][0];            // private slice
  float* xf = reinterpret_cast<float*>(xs);     // f32 view for store scratch

  const int tiles = N >> 4;              // 16-row tiles: 12500
  const int gw = (int)gridDim.x * 4;     // total waves = tile stride (3072)
  const int t0 = (int)blockIdx.x * 4 + wave;
  if (t0 >= tiles) return;               // wave-uniform

  float4 rawA[8], rawB[8];

  // 2-deep prologue: tiles t0 (A) and t0+gw (B) both in flight.
  int tA = t0;
  int tB = t0 + gw;
  load_tile(x, tA, lane, rawA);
  if (tB < tiles) load_tile(x, tB, lane, rawB);

  // process one tile from `raw`; refills `raw` with tile t+2*gw if valid.
  auto process = [&](float4 (&raw)[8], int t) {
    // ---- pack raw -> private LDS slice (bf16, W_PAD layout). ----
    #pragma unroll
    for (int i = 0; i < 8; ++i) {
      int g = i * 64 + lane;
      union { ushort4 u4; __hip_bfloat16 h[4]; } p;
      p.h[0] = __float2bfloat16(raw[i].x);
      p.h[1] = __float2bfloat16(raw[i].y);
      p.h[2] = __float2bfloat16(raw[i].z);
      p.h[3] = __float2bfloat16(raw[i].w);
      *reinterpret_cast<ushort4*>(&xs[(g >> 5) * W_PAD + (g & 31) * 4]) = p.u4;
    }

    // ---- immediately refill this buffer: keeps >=8KB in flight. ----
    const int tn = t + 2 * gw;
    if (tn < tiles) load_tile(x, tn, lane, raw);

    // Within-wave exchange fence (no s_barrier; waves stay independent).
    asm volatile("s_waitcnt lgkmcnt(0)" ::: "memory");
    __builtin_amdgcn_sched_barrier(0);

    // ---- x fragments: lane -> row m, cols s*32+q*8. ----
    bf16x8 af[4];
    #pragma unroll
    for (int s = 0; s < 4; ++s)
      af[s] = *reinterpret_cast<const bf16x8*>(
          &xs[m * W_PAD + s * 32 + q * 8]);

    f32x4 acc[8];
    #pragma unroll
    for (int nt = 0; nt < 8; ++nt) acc[nt] = (f32x4){0.f, 0.f, 0.f, 0.f};
    #pragma unroll
    for (int s = 0; s < 4; ++s) {
      #pragma unroll
      for (int nt = 0; nt < 8; ++nt) {
        bf16x8 wfrag = *reinterpret_cast<const bf16x8*>(
            &Ws[(nt * 16 + m) * W_PAD + s * 32 + q * 8]);
        acc[nt] = __builtin_amdgcn_mfma_f32_16x16x32_bf16(wfrag, af[s],
                                                          acc[nt], 0, 0, 0);
      }
    }

    // ---- coalesced store: LDS transpose in two 8-row halves. ----
    #pragma unroll
    for (int h = 0; h < 2; ++h) {
      if ((m >> 3) == h) {
        #pragma unroll
        for (int nt = 0; nt < 8; ++nt)
          *reinterpret_cast<f32x4*>(
              &xf[(m & 7) * S_PAD + nt * 16 + q * 4]) = acc[nt];
      }
      asm volatile("s_waitcnt lgkmcnt(0)" ::: "memory");
      __builtin_amdgcn_sched_barrier(0);
      float* oh = out + (long)(t * 16 + h * 8) * 128;
      #pragma unroll
      for (int i = 0; i < 4; ++i) {
        int g = i * 64 + lane;
        f32x4 v = *reinterpret_cast<const f32x4*>(
            &xf[(g >> 5) * S_PAD + (g & 31) * 4]);
        *reinterpret_cast<f32x4*>(oh + g * 4) = v;
      }
      // this half's reads must finish before xf is reused (next half / pack)
      asm volatile("s_waitcnt lgkmcnt(0)" ::: "memory");
      __builtin_amdgcn_sched_barrier(0);
    }
  };

  // Alternate A/B; each consume immediately re-issues its buffer.
  while (true) {
    process(rawA, tA);
    tA += 2 * gw;
    if (tB >= tiles) break;
    process(rawB, tB);
    tB += 2 * gw;
    if (tA >= tiles) break;
  }
}

__device__ __forceinline__ int detect_i64(const int* eidx) {
  int or_odd = 0;
  #pragma unroll
  for (int k = 0; k < 16; ++k) or_odd |= eidx[2 * k + 1];
  return or_odd == 0;   // int64 little-endian: high words all zero
}

// Phase A: one block per edge. Read h rows from `out` (pure read), compute
// attn, write contribution vector 0.1*attn*h_src to ws. No races.
__global__ __launch_bounds__(128) void gat_edge_attn(
    const int* __restrict__ eidx,
    const float* __restrict__ a,       // [4, 64]
    const float* __restrict__ h,       // == out, post-GEMM
    float* __restrict__ contrib,       // [E, 128] in ws
    int E) {
  const int e = blockIdx.x;
  const int c = threadIdx.x;
  const bool is64 = detect_i64(eidx);
  const int src = is64 ? eidx[2 * e] : eidx[e];
  const int dst = is64 ? eidx[2 * (E + e)] : eidx[E + e];

  const float hs = h[(long)src * 128 + c];
  const float hd = h[(long)dst * 128 + c];

  const int head = c >> 5, d = c & 31;
  float term = a[head * 64 + d] * hs + a[head * 64 + 32 + d] * hd;
  // reduce over the 32 lanes of this head (heads occupy 32-lane halves)
  term += __shfl_xor(term, 16);
  term += __shfl_xor(term, 8);
  term += __shfl_xor(term, 4);
  term += __shfl_xor(term, 2);
  term += __shfl_xor(term, 1);
  const float attn = term >= 0.f ? term : 0.2f * term;   // leaky_relu(0.2)

  contrib[(long)e * 128 + c] = 0.1f * attn * hs;
}

// Phase B: atomic scatter-add of contributions (duplicate dst handled by HW).
__global__ __launch_bounds__(128) void gat_edge_scatter(
    const int* __restrict__ eidx,
    const float* __restrict__ contrib,
    float* __restrict__ out,
    int E) {
  const int e = blockIdx.x;
  const int c = threadIdx.x;
  const bool is64 = detect_i64(eidx);
  const int dst = is64 ? eidx[2 * (E + e)] : eidx[E + e];
  atomicAdd(&out[(long)dst * 128 + c], contrib[(long)e * 128 + c]);
}

extern "C" void kernel_launch(void* const* d_in, const int* in_sizes, int n_in,
                              void* d_out, int out_size, void* d_ws, size_t ws_size,
                              hipStream_t stream) {
  const float* x  = (const float*)d_in[0];
  const int* eidx = (const int*)d_in[1];
  const float* W  = (const float*)d_in[2];
  const float* a  = (const float*)d_in[3];
  float* out = (float*)d_out;
  float* contrib = (float*)d_ws;     // needs E*128*4 = 256 KB

  const int N = in_sizes[0] / 128;   // 200000
  const int E = in_sizes[1] / 2;     // 500

  const int tiles = N / 16;          // 12500
  int blocks = (tiles + 3) / 4;
  if (blocks > 768) blocks = 768;    // 3 blocks/CU (LDS), 12 wave-streams/CU
  gat_gemm_kernel<<<blocks, 256, 0, stream>>>(x, W, out, N);
  gat_edge_attn<<<E, 128, 0, stream>>>(eidx, a, out, contrib, E);
  gat_edge_scatter<<<E, 128, 0, stream>>>(eidx, contrib, out, E);
}